// Round 12
// baseline (122.314 us; speedup 1.0000x reference)
//
#include <hip/hip_runtime.h>
#include <hip/hip_bf16.h>
#include <cstdint>

typedef __attribute__((ext_vector_type(8))) short bf16x8;
typedef __attribute__((ext_vector_type(4))) float f32x4;
typedef __attribute__((ext_vector_type(16))) float f32x16;
typedef __attribute__((ext_vector_type(4))) unsigned short us4;

#define MFMA16(a, b, c) __builtin_amdgcn_mfma_f32_16x16x32_bf16((a), (b), (c), 0, 0, 0)
#define MFMA32(a, b, c) __builtin_amdgcn_mfma_f32_32x32x16_bf16((a), (b), (c), 0, 0, 0)
#define GLB_PTR(p) ((const __attribute__((address_space(1))) void*)(p))
#define LDS_PTR(p) ((__attribute__((address_space(3))) void*)(p))
#define WAITV(n) asm volatile("s_waitcnt vmcnt(" #n ")" ::: "memory")

__device__ __forceinline__ unsigned short f2bf(float f) {
    union { float f; unsigned u; } v; v.f = f;
    unsigned r = v.u + 0x7fffu + ((v.u >> 16) & 1u);
    return (unsigned short)(r >> 16);
}

__device__ __forceinline__ unsigned cvtpk(float lo, float hi) {
    unsigned r;
    asm("v_cvt_pk_bf16_f32 %0, %1, %2" : "=v"(r) : "v"(lo), "v"(hi));
    return r;
}

// ---------------------------------------------------------------------------
// Stage 0: fp32 -> bf16 casts (3 activations + 4 weights) in one kernel
// ---------------------------------------------------------------------------
struct CastArgs {
    const float* src[7];
    unsigned short* dst[7];
    int n4[7];
};

__global__ __launch_bounds__(256) void cast_f32_bf16(CastArgs a) {
    const int id = blockIdx.y;
    const float4* s = (const float4*)a.src[id];
    us4* d = (us4*)a.dst[id];
    const int n4 = a.n4[id];
    for (int i = blockIdx.x * blockDim.x + threadIdx.x; i < n4;
         i += gridDim.x * blockDim.x) {
        float4 v = s[i];
        us4 o;
        o.x = f2bf(v.x); o.y = f2bf(v.y); o.z = f2bf(v.z); o.w = f2bf(v.w);
        d[i] = o;
    }
}

// ---------------------------------------------------------------------------
// Grouped QKV projection (round-8 proven): C_z = A_z * B_z^T, z = 0,1,2
// Ring-3 LDS pipeline, counted vmcnt. Outputs in PACKED MFMA-FRAGMENT order.
// 128x128 tile, BK=32, 4 waves, grid (32, 8, 3) = 768 blocks = 3/CU.
// ---------------------------------------------------------------------------
struct GemmGroup {
    const unsigned short* A[3];
    const unsigned short* B[3];
    unsigned short* C[3];
};

__global__ __launch_bounds__(256, 2)
void gemm_qkv(GemmGroup gg, int M, int N, int K) {
    __shared__ __align__(16) unsigned short As[3][128 * 32];  // 24 KB
    __shared__ __align__(16) unsigned short Bs[3][128 * 32];  // 24 KB
    const int z = blockIdx.z;
    const unsigned short* __restrict__ A = gg.A[z];
    const unsigned short* __restrict__ B = gg.B[z];
    unsigned short* __restrict__ C = gg.C[z];
    const int t = threadIdx.x;
    const int lane = t & 63, wave = t >> 6;
    const int row0 = blockIdx.x * 128, col0 = blockIdx.y * 128;
    const int wr = (wave >> 1) * 64, wc = (wave & 1) * 64;
    const int r = lane & 15, g = lane >> 4;
    const int srow = t >> 2;
    const int scol = (t & 3) * 8;

#define GSTAGE(sl, k0)                                                         \
    {                                                                          \
        _Pragma("unroll")                                                      \
        for (int i = 0; i < 2; ++i) {                                          \
            const int rr = i * 64 + srow;                                      \
            __builtin_amdgcn_global_load_lds(                                  \
                GLB_PTR(A + (size_t)(row0 + rr) * K + (k0) + scol),            \
                LDS_PTR(&As[sl][rr * 32 + scol]), 16, 0, 0);                   \
            __builtin_amdgcn_global_load_lds(                                  \
                GLB_PTR(B + (size_t)(col0 + rr) * K + (k0) + scol),            \
                LDS_PTR(&Bs[sl][rr * 32 + scol]), 16, 0, 0);                   \
        }                                                                      \
    }

    f32x4 acc[4][4] = {};
    GSTAGE(0, 0);
    GSTAGE(1, 32);

    for (int it = 0; it < 32; ++it) {
        if (it < 31) WAITV(4); else WAITV(0);
        __builtin_amdgcn_s_barrier();
        __builtin_amdgcn_sched_barrier(0);
        if (it + 2 < 32) GSTAGE((it + 2) % 3, (it + 2) * 32);
        const int sl = it % 3;
        bf16x8 a[4], b[4];
#pragma unroll
        for (int m = 0; m < 4; ++m)
            a[m] = *(const bf16x8*)(&As[sl][(wr + m * 16 + r) * 32 + g * 8]);
#pragma unroll
        for (int n = 0; n < 4; ++n)
            b[n] = *(const bf16x8*)(&Bs[sl][(wc + n * 16 + r) * 32 + g * 8]);
        __builtin_amdgcn_s_setprio(1);
#pragma unroll
        for (int m = 0; m < 4; ++m)
#pragma unroll
            for (int n = 0; n < 4; ++n)
                acc[m][n] = MFMA16(a[m], b[n], acc[m][n]);
        __builtin_amdgcn_s_setprio(0);
    }
#undef GSTAGE

    const float sc = (z == 0) ? 0.18033688011112042f : 1.0f;  // 1/8 * log2(e)
#pragma unroll
    for (int m = 0; m < 4; ++m) {
#pragma unroll
        for (int n = 0; n < 4; ++n) {
#pragma unroll
            for (int i = 0; i < 4; ++i) {
                const int row = row0 + wr + m * 16 + g * 4 + i;
                const int col = col0 + wc + n * 16 + r;
                const int b_ = row >> 11, tt = row & 2047;
                const int h = col >> 6, d = col & 63;
                const int bh = b_ * 16 + h;
                size_t idx;
                if (z == 2) {
                    // V^T fragments: dd=d (0..63), kv=tt
                    const int l = (d & 31) + 32 * ((tt >> 3) & 1);
                    idx = ((((size_t)(bh * 32 + (tt >> 6))) * 2 + (d >> 5)) * 4 +
                           ((tt >> 4) & 3)) * 512 + l * 8 + (tt & 7);
                } else {
                    // Q/K fragments: kv/q=tt, dd=d
                    const int l = (tt & 31) + 32 * ((d >> 3) & 1);
                    idx = (((size_t)(bh * 64 + (tt >> 5))) * 4 + (d >> 4)) * 512 +
                          l * 8 + (d & 7);
                }
                C[idx] = f2bf(acc[m][n][i] * sc);
            }
        }
    }
}

// ---------------------------------------------------------------------------
// Output-projection GEMM: C[M,N] = A[M,K] * B[N,K]^T, fp32 out.
// 64x128 tile, ring-3 counted-vmcnt pipeline. grid (64, 8) = 512 = 2/CU.
// ---------------------------------------------------------------------------
__global__ __launch_bounds__(256, 2)
void gemm_wo(const unsigned short* __restrict__ A,
             const unsigned short* __restrict__ B,
             float* __restrict__ C, int M, int N, int K) {
    __shared__ __align__(16) unsigned short As[3][64 * 32];   // 12 KB
    __shared__ __align__(16) unsigned short Bs[3][128 * 32];  // 24 KB
    const int t = threadIdx.x;
    const int lane = t & 63, wave = t >> 6;
    const int row0 = blockIdx.x * 64, col0 = blockIdx.y * 128;
    const int wc = wave * 32;
    const int r = lane & 15, g = lane >> 4;
    const int srow = t >> 2;
    const int scol = (t & 3) * 8;

#define WSTAGE(sl, k0)                                                         \
    {                                                                          \
        __builtin_amdgcn_global_load_lds(                                      \
            GLB_PTR(A + (size_t)(row0 + srow) * K + (k0) + scol),              \
            LDS_PTR(&As[sl][srow * 32 + scol]), 16, 0, 0);                     \
        _Pragma("unroll")                                                      \
        for (int i = 0; i < 2; ++i) {                                          \
            const int rr = i * 64 + srow;                                      \
            __builtin_amdgcn_global_load_lds(                                  \
                GLB_PTR(B + (size_t)(col0 + rr) * K + (k0) + scol),            \
                LDS_PTR(&Bs[sl][rr * 32 + scol]), 16, 0, 0);                   \
        }                                                                      \
    }

    f32x4 acc[4][2] = {};
    WSTAGE(0, 0);
    WSTAGE(1, 32);

    for (int it = 0; it < 32; ++it) {
        if (it < 31) WAITV(3); else WAITV(0);
        __builtin_amdgcn_s_barrier();
        __builtin_amdgcn_sched_barrier(0);
        if (it + 2 < 32) WSTAGE((it + 2) % 3, (it + 2) * 32);
        const int sl = it % 3;
        bf16x8 a[4], b[2];
#pragma unroll
        for (int m = 0; m < 4; ++m)
            a[m] = *(const bf16x8*)(&As[sl][(m * 16 + r) * 32 + g * 8]);
#pragma unroll
        for (int n = 0; n < 2; ++n)
            b[n] = *(const bf16x8*)(&Bs[sl][(wc + n * 16 + r) * 32 + g * 8]);
        __builtin_amdgcn_s_setprio(1);
#pragma unroll
        for (int m = 0; m < 4; ++m)
#pragma unroll
            for (int n = 0; n < 2; ++n)
                acc[m][n] = MFMA16(a[m], b[n], acc[m][n]);
        __builtin_amdgcn_s_setprio(0);
    }
#undef WSTAGE

#pragma unroll
    for (int m = 0; m < 4; ++m)
#pragma unroll
        for (int n = 0; n < 2; ++n)
#pragma unroll
            for (int i = 0; i < 4; ++i) {
                const int row = row0 + m * 16 + g * 4 + i;
                const int col = col0 + wc + n * 16 + r;
                C[(size_t)row * N + col] = acc[m][n][i];
            }
}

// ---------------------------------------------------------------------------
// Flash attention with cross-tile read-ahead, RACE-FIXED ordering:
// per iter: WAITV(counted) -> s_barrier -> STAGE(it+3) -> QK^T(it+1) [MFMA]
// overlapping softmax(it) [VALU] -> PV(it). STAGE is after the barrier so
// slot (it+3)&3 (= tile it-1's slot) is only overwritten once ALL waves
// passed barrier-it, i.e. finished PV(it-1)  [round-11 race: STAGE was
// issued before the barrier -> overwrote a slot still being read].
// Wait counts: outstanding at wait = tiles it+1, it+2 (4 loads each) ->
// WAITV(4) makes tile it+1 resident; tail: WAITV(0) at it>=30.
// Swapped-operand 32x32, packed fragments, ring-4 LDS, no-max softmax
// (shift -12 in MFMA C-init). 4 waves, 128 q-rows/block, grid 512 = 2/CU.
// ---------------------------------------------------------------------------
__global__ __launch_bounds__(256, 2)
void attn_fwd(const unsigned short* __restrict__ Qpk,
              const unsigned short* __restrict__ Kpk,
              const unsigned short* __restrict__ Vpk,
              unsigned short* __restrict__ Y) {
    __shared__ __align__(16) unsigned short kv_lds[4][16][512];  // 64 KB
    const int t = threadIdx.x, lane = t & 63, w = t >> 6;
    const int q31 = lane & 31, hi = lane >> 5;

    const int flat = blockIdx.x;
    const int swz = (flat & 7) * 64 + (flat >> 3);
    const int qt = swz & 15, bh = swz >> 4;
    const int qb0 = qt * 128;

    const unsigned short* Qb = Qpk + ((size_t)(bh * 64 + qt * 4 + w)) * 2048;
    const unsigned short* Kb = Kpk + (size_t)bh * 131072;
    const unsigned short* Vb = Vpk + (size_t)bh * 131072;

    bf16x8 qf[4];
#pragma unroll
    for (int s = 0; s < 4; ++s)
        qf[s] = *(const bf16x8*)(Qb + s * 512 + lane * 8);
    WAITV(0);  // isolate qf loads from the counted stage queue

    f32x16 o0 = {}, o1 = {};
    float l_ = 0.f;

#define STAGE(sl, kv0)                                                         \
    {                                                                          \
        _Pragma("unroll")                                                      \
        for (int i = 0; i < 4; ++i) {                                          \
            const int f = w * 4 + i;                                           \
            const unsigned short* src =                                        \
                (f < 8 ? Kb : Vb) + (kv0) * 64 + (f & 7) * 512 + lane * 8;     \
            __builtin_amdgcn_global_load_lds(                                  \
                GLB_PTR(src), LDS_PTR(&kv_lds[sl][f][lane * 8]), 16, 0, 0);    \
        }                                                                      \
    }

    STAGE(0, 0);
    STAGE(1, 64);
    STAGE(2, 128);

    // prologue: tile 0 resident -> QK(0)
    WAITV(8);
    __builtin_amdgcn_s_barrier();
    __builtin_amdgcn_sched_barrier(0);
    f32x16 sA0, sA1;
    {
        bf16x8 kf[8];
#pragma unroll
        for (int i = 0; i < 8; ++i)
            kf[i] = *(const bf16x8*)(&kv_lds[0][i][lane * 8]);
#pragma unroll
        for (int r = 0; r < 16; ++r) { sA0[r] = -12.f; sA1[r] = -12.f; }
        __builtin_amdgcn_s_setprio(1);
#pragma unroll
        for (int s = 0; s < 4; ++s) sA0 = MFMA32(kf[s], qf[s], sA0);
#pragma unroll
        for (int s = 0; s < 4; ++s) sA1 = MFMA32(kf[4 + s], qf[s], sA1);
        __builtin_amdgcn_s_setprio(0);
    }

    for (int it = 0; it < 32; ++it) {
        // counted wait: tile it+1 resident after this (tail-adjusted)
        if (it < 30) WAITV(4); else WAITV(0);
        __builtin_amdgcn_s_barrier();   // ALL waves' tile-(it+1) frags in;
        __builtin_amdgcn_sched_barrier(0);  // all waves done with PV(it-1)
        if (it + 3 < 32) STAGE((it + 3) & 3, (it + 3) * 64);

        // --- QK^T(it+1): MFMA cluster, independent of softmax(it) below ---
        f32x16 sN0, sN1;
        if (it + 1 < 32) {
            const int sln = (it + 1) & 3;
            bf16x8 kf[8];
#pragma unroll
            for (int i = 0; i < 8; ++i)
                kf[i] = *(const bf16x8*)(&kv_lds[sln][i][lane * 8]);
#pragma unroll
            for (int r = 0; r < 16; ++r) { sN0[r] = -12.f; sN1[r] = -12.f; }
#pragma unroll
            for (int s = 0; s < 4; ++s) sN0 = MFMA32(kf[s], qf[s], sN0);
#pragma unroll
            for (int s = 0; s < 4; ++s) sN1 = MFMA32(kf[4 + s], qf[s], sN1);
        }

        // --- softmax(it): p = exp2(s - 12), accumulate l (VALU/trans) ---
        float p[32];
#pragma unroll
        for (int r = 0; r < 16; ++r) p[r] = __builtin_amdgcn_exp2f(sA0[r]);
#pragma unroll
        for (int r = 0; r < 16; ++r) p[16 + r] = __builtin_amdgcn_exp2f(sA1[r]);

        float sm[16];
#pragma unroll
        for (int r = 0; r < 16; ++r) sm[r] = p[r] + p[16 + r];
#pragma unroll
        for (int d = 8; d > 0; d >>= 1)
#pragma unroll
            for (int r = 0; r < d; ++r) sm[r] += sm[r + d];
        l_ += sm[0] + __shfl_xor(sm[0], 32);

        unsigned c[16];
#pragma unroll
        for (int i = 0; i < 16; ++i) c[i] = cvtpk(p[2 * i], p[2 * i + 1]);

        // --- PV(it) ---
        const int sl = it & 3;
        bf16x8 vf[8];
#pragma unroll
        for (int i = 0; i < 8; ++i)
            vf[i] = *(const bf16x8*)(&kv_lds[sl][8 + i][lane * 8]);

        __builtin_amdgcn_s_setprio(1);
#pragma unroll
        for (int s = 0; s < 4; ++s) {
            const int base = (s >> 1) * 8 + (s & 1) * 4;
            unsigned a0 = c[base + 0], b0 = c[base + 2];
            unsigned a1 = c[base + 1], b1 = c[base + 3];
            asm volatile("v_permlane32_swap_b32 %0, %1" : "+v"(a0), "+v"(b0));
            asm volatile("v_permlane32_swap_b32 %0, %1" : "+v"(a1), "+v"(b1));
            union { unsigned u[4]; bf16x8 v; } pb;
            pb.u[0] = a0; pb.u[1] = a1; pb.u[2] = b0; pb.u[3] = b1;
            o0 = MFMA32(vf[s], pb.v, o0);
            o1 = MFMA32(vf[4 + s], pb.v, o1);
        }
        __builtin_amdgcn_s_setprio(0);

        sA0 = sN0;
        sA1 = sN1;
    }
#undef STAGE

    __syncthreads();  // full drain before LDS reuse for the epilogue

    unsigned short (*yb)[68] = (unsigned short (*)[68])kv_lds;
    const float rinv = 1.0f / l_;
#pragma unroll
    for (int r = 0; r < 16; ++r) {
        const int dd = (r & 3) + 8 * (r >> 2) + 4 * hi;
        yb[w * 32 + q31][dd] = f2bf(o0[r] * rinv);
        yb[w * 32 + q31][32 + dd] = f2bf(o1[r] * rinv);
    }
    __syncthreads();
    const int b_ = bh >> 4, h = bh & 15;
#pragma unroll
    for (int i = 0; i < 8; ++i) {
        const int row = i * 16 + (t >> 4);
        const int col = (t & 15) * 4;
        *(us4*)(Y + ((size_t)(b_ * 2048 + qb0 + row)) * 1024 + h * 64 + col) =
            *(const us4*)(&yb[row][col]);
    }
}

// ---------------------------------------------------------------------------
// Launch
// ---------------------------------------------------------------------------
extern "C" void kernel_launch(void* const* d_in, const int* in_sizes, int n_in,
                              void* d_out, int out_size, void* d_ws, size_t ws_size,
                              hipStream_t stream) {
    // inputs: query, key, value [2,2048,1024] f32; Wq,Wk,Wv,Wo [1024,1024] f32
    uint8_t* ws = (uint8_t*)d_ws;
    unsigned short* xq = (unsigned short*)(ws + 0);         // 8 MB (aliased as y later)
    unsigned short* xk = (unsigned short*)(ws + 8388608);
    unsigned short* xv = (unsigned short*)(ws + 16777216);
    unsigned short* wq = (unsigned short*)(ws + 25165824);  // 2 MB each
    unsigned short* wk = (unsigned short*)(ws + 27262976);
    unsigned short* wv = (unsigned short*)(ws + 29360128);
    unsigned short* wo = (unsigned short*)(ws + 31457280);
    unsigned short* Qp = (unsigned short*)(ws + 33554432);  // packed frags (pre-scaled)
    unsigned short* Kp = (unsigned short*)(ws + 41943040);  // packed frags
    unsigned short* Vp = (unsigned short*)(ws + 50331648);  // packed V^T frags
    unsigned short* y  = xq;  // alias: xq dead after Q projection

    CastArgs ca;
    ca.src[0] = (const float*)d_in[0]; ca.dst[0] = xq; ca.n4[0] = 4194304 / 4;
    ca.src[1] = (const float*)d_in[1]; ca.dst[1] = xk; ca.n4[1] = 4194304 / 4;
    ca.src[2] = (const float*)d_in[2]; ca.dst[2] = xv; ca.n4[2] = 4194304 / 4;
    ca.src[3] = (const float*)d_in[3]; ca.dst[3] = wq; ca.n4[3] = 1048576 / 4;
    ca.src[4] = (const float*)d_in[4]; ca.dst[4] = wk; ca.n4[4] = 1048576 / 4;
    ca.src[5] = (const float*)d_in[5]; ca.dst[5] = wv; ca.n4[5] = 1048576 / 4;
    ca.src[6] = (const float*)d_in[6]; ca.dst[6] = wo; ca.n4[6] = 1048576 / 4;
    cast_f32_bf16<<<dim3(512, 7), 256, 0, stream>>>(ca);

    // grouped QKV projections -> packed fragment layouts
    GemmGroup gg;
    gg.A[0] = xq; gg.B[0] = wq; gg.C[0] = Qp;
    gg.A[1] = xk; gg.B[1] = wk; gg.C[1] = Kp;
    gg.A[2] = xv; gg.B[2] = wv; gg.C[2] = Vp;
    gemm_qkv<<<dim3(32, 8, 3), 256, 0, stream>>>(gg, 4096, 1024, 1024);

    // fused flash attention -> y [B,T,C] bf16 (aliases xq)
    attn_fwd<<<dim3(512), 256, 0, stream>>>(Qp, Kp, Vp, y);

    // output projection -> fp32 d_out
    gemm_wo<<<dim3(64, 8), 256, 0, stream>>>(y, wo, (float*)d_out, 4096, 1024, 1024);
}